// Round 9
// baseline (85.912 us; speedup 1.0000x reference)
//
#include <hip/hip_runtime.h>
#include <hip/hip_fp16.h>
#include <math.h>

#define B_ 16
#define F_ 256
#define T_ 2048
#define K_ 20
#define OUTK 21
#define CTOFF (B_ * T_ * F_ * 2)   // byte offset of cth table relative to zth (16 MB)

typedef _Float16 half8 __attribute__((ext_vector_type(8)));
typedef float f32x4 __attribute__((ext_vector_type(4)));

// Transpose z [F][T] / c [F][T+1] (drop col 0) -> f16 [T][F] per batch,
// plus per-column sqrt(sum of squares) in fp32 (exact, from fp32 source).
__global__ __launch_bounds__(256) void transpose_norm2_kernel(
    const float* __restrict__ z, const float* __restrict__ c,
    ushort* __restrict__ zth, ushort* __restrict__ cth,
    float* __restrict__ snz, float* __restrict__ snc)
{
    __shared__ float tile[256][33];  // 256 f x 32 t, +1 pad
    int which = blockIdx.z;
    const float* src = which ? c : z;
    ushort* dst = which ? cth : zth;
    float* nrm = which ? snc : snz;
    int Lsrc = which ? (T_ + 1) : T_;
    int co   = which;                 // c drops the start token

    int b  = blockIdx.y;
    int t0 = blockIdx.x * 32;
    const float* srcb = src + (size_t)b * F_ * Lsrc;
    int tl = threadIdx.x & 31;   // t within tile
    int fl = threadIdx.x >> 5;   // 0..7
#pragma unroll
    for (int i = 0; i < 32; ++i) {
        int f = i * 8 + fl;
        tile[f][tl] = srcb[(size_t)f * Lsrc + (t0 + tl + co)];
    }
    __syncthreads();
    // write phase: pack 2 adjacent f into one uint; 128 lanes cover a row, 2 rows/iter
    int l   = threadIdx.x & 127;
    int rhi = threadIdx.x >> 7;
#pragma unroll
    for (int j2 = 0; j2 < 16; ++j2) {
        int row = j2 * 2 + rhi;
        float a  = tile[2 * l][row];
        float bb = tile[2 * l + 1][row];
        unsigned u = ((unsigned)__half_as_ushort(__float2half(bb)) << 16)
                   |  (unsigned)__half_as_ushort(__float2half(a));
        unsigned* drow = (unsigned*)(dst + ((size_t)b * T_ + t0 + row) * F_);
        drow[l] = u;
    }
    if (threadIdx.x < 32) {
        float s = 0.f;
#pragma unroll 8
        for (int f = 0; f < 256; ++f) { float v = tile[f][threadIdx.x]; s += v * v; }
        nrm[b * T_ + t0 + threadIdx.x] = sqrtf(s);
    }
}

__device__ __forceinline__ unsigned fold16(unsigned long long x) {
    // target slot n occupies ballot bits n, n+16, n+32, n+48 (the 4 k-groups)
    return (unsigned)(x & 0xFFFFu) & (unsigned)((x >> 16) & 0xFFFFu)
         & (unsigned)((x >> 32) & 0xFFFFu) & (unsigned)(x >> 48);
}
__device__ __forceinline__ bool eq16(uint4 a, uint4 b) {
    return (a.x == b.x) && (a.y == b.y) && (a.z == b.z) && (a.w == b.w);
}

// One 64-lane wave per (b,t). MFMA formulation:
//   A (16x32 slice) = z row broadcast to all 16 rows (4-distinct-addr load)
//   B (32x16 slice) = 16 target rows, slot = lane&15, 16B at 64*s+16*(lane>>4)
//   D[m][n] = dot(z, target_n) for every m -> lane k holds target k's dot.
// Two sets: set0 slots {c, neg1..15}, set1 slots {neg16..20, dup}. 16 MFMAs/t.
__global__ __launch_bounds__(256, 3) void sim_kernel(
    const ushort* __restrict__ zth, const ushort* __restrict__ cth,
    const float* __restrict__ snz, const float* __restrict__ snc,
    const int* __restrict__ inds, float* __restrict__ out)
{
    int i = blockIdx.x;                               // 8192 blocks, 4 waves each
    int b = (i & 7) | ((i >= 4096) ? 8 : 0);          // batch b on XCD b&7 (L2-resident table)
    int wid = threadIdx.x >> 6;
    int t = (((i >> 3) & 511) << 2) + wid;
    int lane = threadIdx.x & 63;
    int slot = lane & 15;                             // target slot within set
    int kg = lane >> 4;                               // k-group 0..3
    int bt = __builtin_amdgcn_readfirstlane((b << 11) + t);

    const int* myinds = inds + bt * K_;

    // epilogue norm gather (lane k -> norm of its target), issued early
    int lm1 = (lane >= 1 && lane <= K_) ? (lane - 1) : 0;
    int myidx = myinds[lm1];
    const float* np = (lane == 0) ? (snc + bt)
                    : ((lane <= K_) ? (snz + ((b << 11) + myidx)) : (snz + bt));
    float stn = *np;
    float szn = snz[bt];                              // uniform

    // per-lane target-row byte offsets (slot -> output k: set0 k=slot, set1 k=16+slot)
    int i0 = myinds[(slot >= 1) ? (slot - 1) : 0];    // set0 slots 1..15 -> inds[0..14]
    int i1 = myinds[(slot <= 4) ? (15 + slot) : 19];  // set1 slots 0..4 -> inds[15..19]
    unsigned zbase = (unsigned)(b << 11) * 512u;
    unsigned cbyte = (unsigned)CTOFF + (unsigned)bt * 512u;
    unsigned rb0 = (slot == 0) ? cbyte : (zbase + (unsigned)i0 * 512u);
    unsigned rb1 = zbase + (unsigned)i1 * 512u;
    unsigned qoff = (unsigned)kg * 16u;
    unsigned abase = (unsigned)bt * 512u;             // z row (A operand)

    const char* tbl = (const char*)zth;

    uint4 Bf0[8], Bf1[8], Af[8], c0;
#pragma unroll
    for (int s = 0; s < 8; ++s) {
        Bf0[s] = *(const uint4*)(tbl + rb0 + 64u * s + qoff);
        Bf1[s] = *(const uint4*)(tbl + rb1 + 64u * s + qoff);
        Af[s]  = *(const uint4*)(tbl + abase + 64u * s + qoff);
    }
    c0 = *(const uint4*)(tbl + cbyte + qoff);         // c slice 0 (for mask screen)

    // hard scheduler fence: all 25 loads stay issued up-front
    __builtin_amdgcn_sched_barrier(0);

    f32x4 acc0 = {0.f, 0.f, 0.f, 0.f};
    f32x4 acc1 = {0.f, 0.f, 0.f, 0.f};
#pragma unroll
    for (int s = 0; s < 8; ++s) {
        half8 a = __builtin_bit_cast(half8, Af[s]);
        acc0 = __builtin_amdgcn_mfma_f32_16x16x32_f16(
                   a, __builtin_bit_cast(half8, Bf0[s]), acc0, 0, 0, 0);
        acc1 = __builtin_amdgcn_mfma_f32_16x16x32_f16(
                   a, __builtin_bit_cast(half8, Bf1[s]), acc1, 0, 0, 0);
    }

    // exact neg_is_pos: slice-0 (16B/lane) screen, uniform rare full recheck
    bool e0 = eq16(Bf0[0], c0);
    bool e1 = eq16(Bf1[0], c0);
    unsigned m0 = fold16(__ballot(e0)) & 0xFFFEu;     // slot0 = positive, never masked
    unsigned m1 = fold16(__ballot(e1)) & 0x001Fu;
    unsigned mb = 0;
    if (m0 | m1) {                                    // uniform branch, ~never taken
        bool f0 = e0, f1 = e1;
#pragma unroll
        for (int s = 1; s < 8; ++s) {
            uint4 cs = *(const uint4*)(tbl + cbyte + 64u * s + qoff);
            f0 = f0 && eq16(Bf0[s], cs);
            f1 = f1 && eq16(Bf1[s], cs);
        }
        unsigned fm0 = fold16(__ballot(f0)) & 0xFFFEu;
        unsigned fm1 = fold16(__ballot(f1)) & 0x001Fu;
        mb = fm0 | (fm1 << 16);
    }

    // extraction: lane k<16 holds set0 slot k in acc0[0]; lanes 16..20 pull
    // set1 slot (lane-16) from lane (lane&15)'s acc1[0].
    float d1 = __shfl(acc1[0], lane & 15);
    float d  = (lane < 16) ? acc0[0] : d1;

    if (lane < OUTK) {
        float den = fmaxf(szn * stn, 1e-8f);
        float v = (d / den) * 2.0f;                   // / TEMP, TEMP = 0.5
        if ((mb >> lane) & 1u) v = -INFINITY;
        out[(size_t)bt * OUTK + lane] = v;
    }
}

extern "C" void kernel_launch(void* const* d_in, const int* in_sizes, int n_in,
                              void* d_out, int out_size, void* d_ws, size_t ws_size,
                              hipStream_t stream)
{
    const float* z    = (const float*)d_in[0];
    const float* c    = (const float*)d_in[1];
    const int*   inds = (const int*)d_in[2];
    float* out = (float*)d_out;

    char* ws = (char*)d_ws;
    size_t th_bytes = (size_t)B_ * T_ * F_ * sizeof(ushort);  // 16 MB
    ushort* zth = (ushort*)ws;
    ushort* cth = (ushort*)(ws + th_bytes);                   // zth + CTOFF
    float*  snz = (float*)(ws + 2 * th_bytes);
    float*  snc = snz + B_ * T_;

    dim3 tb(256), tg(T_ / 32, B_, 2);
    transpose_norm2_kernel<<<tg, tb, 0, stream>>>(z, c, zth, cth, snz, snc);
    sim_kernel<<<dim3(B_ * T_ / 4), dim3(256), 0, stream>>>(zth, cth, snz, snc, inds, out);
}

// Round 10
// 48.669 us; speedup vs baseline: 1.7652x; 1.7652x over previous
//
#include <hip/hip_runtime.h>
#include <hip/hip_fp16.h>
#include <math.h>

#define B_ 16
#define F_ 256
#define T_ 2048
#define K_ 20
#define OUTK 21
#define NPAIR 11
#define CTOFF (B_ * T_ * F_ * 2)   // byte offset of cth table relative to zth (16 MB)

typedef _Float16 half2v __attribute__((ext_vector_type(2)));

__device__ __forceinline__ half2v h2(unsigned u) { return __builtin_bit_cast(half2v, u); }
__device__ __forceinline__ float fdot2f(unsigned a, unsigned b, float c) {
#if __has_builtin(__builtin_amdgcn_fdot2)
    return __builtin_amdgcn_fdot2(h2(a), h2(b), c, false);
#else
    half2v x = h2(a), y = h2(b);
    return fmaf((float)x[1], (float)y[1], fmaf((float)x[0], (float)y[0], c));
#endif
}

// Transpose z [F][T] / c [F][T+1] (drop col 0) -> f16 [T][F] per batch,
// plus per-column sqrt(sum of squares) in fp32 (exact, from fp32 source).
__global__ __launch_bounds__(256) void transpose_norm2_kernel(
    const float* __restrict__ z, const float* __restrict__ c,
    ushort* __restrict__ zth, ushort* __restrict__ cth,
    float* __restrict__ snz, float* __restrict__ snc)
{
    __shared__ float tile[256][33];  // 256 f x 32 t, +1 pad
    int which = blockIdx.z;
    const float* src = which ? c : z;
    ushort* dst = which ? cth : zth;
    float* nrm = which ? snc : snz;
    int Lsrc = which ? (T_ + 1) : T_;
    int co   = which;                 // c drops the start token

    int b  = blockIdx.y;
    int t0 = blockIdx.x * 32;
    const float* srcb = src + (size_t)b * F_ * Lsrc;
    int tl = threadIdx.x & 31;   // t within tile
    int fl = threadIdx.x >> 5;   // 0..7
#pragma unroll
    for (int i = 0; i < 32; ++i) {
        int f = i * 8 + fl;
        tile[f][tl] = srcb[(size_t)f * Lsrc + (t0 + tl + co)];
    }
    __syncthreads();
    // write phase: pack 2 adjacent f into one uint; 128 lanes cover a row, 2 rows/iter
    int l   = threadIdx.x & 127;
    int rhi = threadIdx.x >> 7;
#pragma unroll
    for (int j2 = 0; j2 < 16; ++j2) {
        int row = j2 * 2 + rhi;
        float a  = tile[2 * l][row];
        float bb = tile[2 * l + 1][row];
        unsigned u = ((unsigned)__half_as_ushort(__float2half(bb)) << 16)
                   |  (unsigned)__half_as_ushort(__float2half(a));
        unsigned* drow = (unsigned*)(dst + ((size_t)b * T_ + t0 + row) * F_);
        drow[l] = u;
    }
    if (threadIdx.x < 32) {
        float s = 0.f;
#pragma unroll 8
        for (int f = 0; f < 256; ++f) { float v = tile[f][threadIdx.x]; s += v * v; }
        nrm[b * T_ + t0 + threadIdx.x] = sqrtf(s);
    }
}

// Sum within each 32-lane half (pure VALU DPP). Valid in lane 31 (lo) / 63 (hi).
__device__ __forceinline__ float dpp_half_sum(float x) {
    x += __int_as_float(__builtin_amdgcn_mov_dpp(__float_as_int(x), 0x111, 0xF, 0xF, true)); // row_shr:1
    x += __int_as_float(__builtin_amdgcn_mov_dpp(__float_as_int(x), 0x112, 0xF, 0xF, true)); // row_shr:2
    x += __int_as_float(__builtin_amdgcn_mov_dpp(__float_as_int(x), 0x114, 0xF, 0xF, true)); // row_shr:4
    x += __int_as_float(__builtin_amdgcn_mov_dpp(__float_as_int(x), 0x118, 0xF, 0xF, true)); // row_shr:8
    x += __int_as_float(__builtin_amdgcn_mov_dpp(__float_as_int(x), 0x142, 0xF, 0xF, true)); // row_bcast:15
    return x;
}

// ---- per-t phases as macros (distinct registers per suffix S) ----

#define T_TV_LOADS(S) \
    uint4 tv##S[NPAIR]; \
    { unsigned olo = cbyte##S; \
      unsigned ohi = zbase + (unsigned)__builtin_amdgcn_readlane(idxv##S, 0) * 512u; \
      tv##S[0] = *(const uint4*)(tbl + ((hi ? ohi : olo) + laneoff)); } \
    _Pragma("unroll") \
    for (int p = 1; p < NPAIR; ++p) { \
        unsigned ilo = (unsigned)__builtin_amdgcn_readlane(idxv##S, 2 * p - 1); \
        unsigned ihi = (unsigned)__builtin_amdgcn_readlane(idxv##S, (p == 10) ? 19 : 2 * p); \
        unsigned off = zbase + (hi ? ihi : ilo) * 512u + laneoff; \
        tv##S[p] = *(const uint4*)(tbl + off); \
    }

#define T_COMPUTE(S, tsel) \
    { \
        float dz[NPAIR]; \
        _Pragma("unroll") \
        for (int p = 0; p < NPAIR; ++p) { \
            float d = fdot2f(tv##S[p].x, zv##S.x, 0.f); \
            d = fdot2f(tv##S[p].y, zv##S.y, d); \
            d = fdot2f(tv##S[p].z, zv##S.z, d); \
            d = fdot2f(tv##S[p].w, zv##S.w, d); \
            dz[p] = d; \
        } \
        unsigned mb = 0; \
        _Pragma("unroll") \
        for (int p = 0; p < NPAIR; ++p) { \
            unsigned long long ball = __ballot(tv##S[p].x == cv##S.x); \
            unsigned blo = (unsigned)ball, bhi = (unsigned)(ball >> 32); \
            if (blo == 0xFFFFFFFFu || bhi == 0xFFFFFFFFu) { \
                bool full = (tv##S[p].x == cv##S.x) && (tv##S[p].y == cv##S.y) && \
                            (tv##S[p].z == cv##S.z) && (tv##S[p].w == cv##S.w); \
                unsigned long long b2 = __ballot(full); \
                if ((unsigned)b2 == 0xFFFFFFFFu)          mb |= 1u << (2 * p); \
                if ((unsigned)(b2 >> 32) == 0xFFFFFFFFu)  mb |= 1u << (2 * p + 1); \
            } \
        } \
        mb &= ~1u; \
        _Pragma("unroll") \
        for (int p = 0; p < NPAIR; ++p) dz[p] = dpp_half_sum(dz[p]); \
        if (hl == 31) { \
            _Pragma("unroll") \
            for (int p = 0; p < NPAIR; ++p) sd[wid * 64 + (tsel) * 32 + hi + 2 * p] = dz[p]; \
        } \
        if (lane < OUTK) { \
            float d = sd[wid * 64 + (tsel) * 32 + lane]; \
            float den = fmaxf(szn##S * stn##S, 1e-8f); \
            float v = (d / den) * 2.0f; \
            if ((mb >> lane) & 1u) v = -INFINITY; \
            out[(size_t)bt##S * OUTK + lane] = v; \
        } \
    }

// One 64-lane wave per TWO (b,t) rows (t and t+1024): software-pipelined so
// tvB loads + norm gathers stay in flight across A's entire compute phase.
// Load order exploits vmcnt in-order semantics: readlane(idxvB) happens after
// tvA issues, so tvB never waits on tvA.
__global__ __launch_bounds__(256) void sim_kernel(
    const ushort* __restrict__ zth, const ushort* __restrict__ cth,
    const float* __restrict__ snz, const float* __restrict__ snc,
    const int* __restrict__ inds, float* __restrict__ out)
{
    __shared__ float sd[256];                         // 4 waves x 2 t x 32 slots
    int i = blockIdx.x;                               // 4096 blocks, 4 waves each
    int b = (i & 7) | ((i >= 2048) ? 8 : 0);          // batch b on XCD b&7 (L2-resident table)
    int wid = threadIdx.x >> 6;
    int lane = threadIdx.x & 63;
    int hl = lane & 31;                               // pos within half
    int hi = lane >> 5;                               // which half
    int tA = (((i >> 3) & 255) << 2) + wid;
    int btA = __builtin_amdgcn_readfirstlane((b << 11) + tA);
    int btB = btA + 1024;

    const char* tbl = (const char*)zth;
    unsigned zbase   = (unsigned)(b << 11) * 512u;    // batch base byte offset
    unsigned laneoff = (unsigned)hl * 16u;
    unsigned cbyteA = (unsigned)CTOFF + (unsigned)btA * 512u;
    unsigned cbyteB = (unsigned)CTOFF + (unsigned)btB * 512u;

    // PH1: index rows (lane k holds inds[k])
    int idxvA = (inds + btA * K_)[(lane < K_) ? lane : 0];
    int idxvB = (inds + btB * K_)[(lane < K_) ? lane : 0];

    // PH2: own z/c rows + uniform norms
    uint4 zvA = ((const uint4*)(zth + (size_t)btA * F_))[hl];
    uint4 cvA = ((const uint4*)(cth + (size_t)btA * F_))[hl];
    uint4 zvB = ((const uint4*)(zth + (size_t)btB * F_))[hl];
    uint4 cvB = ((const uint4*)(cth + (size_t)btB * F_))[hl];
    float sznA = snz[btA];
    float sznB = snz[btB];

    // PH3/PH4: target rows (two per wave-load: lanes 0-31 = k=2p, 32-63 = k=2p+1)
    T_TV_LOADS(A)
    T_TV_LOADS(B)

    // PH5: per-lane target-norm gathers; index via lane shift (no extra idx load)
    int myidxA = __shfl_up(idxvA, 1);                 // lane k -> inds[k-1]
    int myidxB = __shfl_up(idxvB, 1);
    const float* npA = (lane == 0) ? (snc + btA)
                     : ((lane <= K_) ? (snz + ((b << 11) + myidxA)) : (snz + btA));
    const float* npB = (lane == 0) ? (snc + btB)
                     : ((lane <= K_) ? (snz + ((b << 11) + myidxB)) : (snz + btB));
    float stnA = *npA;
    float stnB = *npB;

    // hard scheduler fence: every load above stays issued before any compute
    __builtin_amdgcn_sched_barrier(0);

    T_COMPUTE(A, 0)
    T_COMPUTE(B, 1)
}

extern "C" void kernel_launch(void* const* d_in, const int* in_sizes, int n_in,
                              void* d_out, int out_size, void* d_ws, size_t ws_size,
                              hipStream_t stream)
{
    const float* z    = (const float*)d_in[0];
    const float* c    = (const float*)d_in[1];
    const int*   inds = (const int*)d_in[2];
    float* out = (float*)d_out;

    char* ws = (char*)d_ws;
    size_t th_bytes = (size_t)B_ * T_ * F_ * sizeof(ushort);  // 16 MB
    ushort* zth = (ushort*)ws;
    ushort* cth = (ushort*)(ws + th_bytes);                   // zth + CTOFF
    float*  snz = (float*)(ws + 2 * th_bytes);
    float*  snc = snz + B_ * T_;

    dim3 tb(256), tg(T_ / 32, B_, 2);
    transpose_norm2_kernel<<<tg, tb, 0, stream>>>(z, c, zth, cth, snz, snc);
    sim_kernel<<<dim3(B_ * T_ / 8), dim3(256), 0, stream>>>(zth, cth, snz, snc, inds, out);
}

// Round 11
// 44.789 us; speedup vs baseline: 1.9182x; 1.0866x over previous
//
#include <hip/hip_runtime.h>
#include <hip/hip_fp16.h>
#include <math.h>

#define B_ 16
#define F_ 256
#define T_ 2048
#define K_ 20
#define OUTK 21
#define NPAIR 11
#define CTOFF (B_ * T_ * F_ * 2)   // byte offset of cth table relative to zth (16 MB)

typedef _Float16 half2v __attribute__((ext_vector_type(2)));

__device__ __forceinline__ half2v h2(unsigned u) { return __builtin_bit_cast(half2v, u); }
__device__ __forceinline__ float fdot2f(unsigned a, unsigned b, float c) {
#if __has_builtin(__builtin_amdgcn_fdot2)
    return __builtin_amdgcn_fdot2(h2(a), h2(b), c, false);
#else
    half2v x = h2(a), y = h2(b);
    return fmaf((float)x[1], (float)y[1], fmaf((float)x[0], (float)y[0], c));
#endif
}

// Transpose z [F][T] / c [F][T+1] (drop col 0) -> UNIT-NORM f16 rows [T][F]
// per batch. Norm computed in exact fp32 from the staged column; rows are
// stored pre-divided by their norm so sim's dot IS the cosine (no norm
// gathers, no sqrt/div in sim). Zero-norm -> scale 0 -> dot 0 (matches
// reference's eps-clamped 0).
__global__ __launch_bounds__(256) void transpose_norm2_kernel(
    const float* __restrict__ z, const float* __restrict__ c,
    ushort* __restrict__ zth, ushort* __restrict__ cth)
{
    __shared__ float tile[256][33];  // 256 f x 32 t, +1 pad
    __shared__ float sc[32];         // per-column 1/norm
    int which = blockIdx.z;
    const float* src = which ? c : z;
    ushort* dst = which ? cth : zth;
    int Lsrc = which ? (T_ + 1) : T_;
    int co   = which;                 // c drops the start token

    int b  = blockIdx.y;
    int t0 = blockIdx.x * 32;
    const float* srcb = src + (size_t)b * F_ * Lsrc;
    int tl = threadIdx.x & 31;   // t within tile
    int fl = threadIdx.x >> 5;   // 0..7
#pragma unroll
    for (int i = 0; i < 32; ++i) {
        int f = i * 8 + fl;
        tile[f][tl] = srcb[(size_t)f * Lsrc + (t0 + tl + co)];
    }
    __syncthreads();
    if (threadIdx.x < 32) {
        float s = 0.f;
#pragma unroll 8
        for (int f = 0; f < 256; ++f) { float v = tile[f][threadIdx.x]; s += v * v; }
        float n = sqrtf(s);
        sc[threadIdx.x] = (n > 0.f) ? (1.0f / n) : 0.f;
    }
    __syncthreads();
    // write phase: pack 2 adjacent f into one uint; 128 lanes cover a row, 2 rows/iter
    int l   = threadIdx.x & 127;
    int rhi = threadIdx.x >> 7;
#pragma unroll
    for (int j2 = 0; j2 < 16; ++j2) {
        int row = j2 * 2 + rhi;
        float s  = sc[row];
        float a  = tile[2 * l][row] * s;
        float bb = tile[2 * l + 1][row] * s;
        unsigned u = ((unsigned)__half_as_ushort(__float2half(bb)) << 16)
                   |  (unsigned)__half_as_ushort(__float2half(a));
        unsigned* drow = (unsigned*)(dst + ((size_t)b * T_ + t0 + row) * F_);
        drow[l] = u;
    }
}

// Sum within each 32-lane half (pure VALU DPP). Valid in lane 31 (lo) / 63 (hi).
__device__ __forceinline__ float dpp_half_sum(float x) {
    x += __int_as_float(__builtin_amdgcn_mov_dpp(__float_as_int(x), 0x111, 0xF, 0xF, true)); // row_shr:1
    x += __int_as_float(__builtin_amdgcn_mov_dpp(__float_as_int(x), 0x112, 0xF, 0xF, true)); // row_shr:2
    x += __int_as_float(__builtin_amdgcn_mov_dpp(__float_as_int(x), 0x114, 0xF, 0xF, true)); // row_shr:4
    x += __int_as_float(__builtin_amdgcn_mov_dpp(__float_as_int(x), 0x118, 0xF, 0xF, true)); // row_shr:8
    x += __int_as_float(__builtin_amdgcn_mov_dpp(__float_as_int(x), 0x142, 0xF, 0xF, true)); // row_bcast:15
    return x;
}

// One 64-lane wave per (b,t). Two UNIT targets per wave-load (uint4: lanes
// 0-31 = target 2p, lanes 32-63 = target 2p+1). Offsets via inline readlane
// (pure SGPR, no array, no scratch). All 11 loads fenced in flight by
// sched_barrier(0). logit = 2 * dot (tables are unit rows). Parallel lane-k
// epilogue via tiny LDS.
__global__ __launch_bounds__(256, 4) void sim_kernel(
    const ushort* __restrict__ zth, const ushort* __restrict__ cth,
    const int* __restrict__ inds, float* __restrict__ out)
{
    __shared__ float sd[128];                         // 4 waves x 32 slots
    int i = blockIdx.x;                               // 8192 blocks, 4 waves each
    int b = (i & 7) | ((i >= 4096) ? 8 : 0);          // batch b on XCD b&7 (L2-resident table)
    int wid = threadIdx.x >> 6;
    int t = (((i >> 3) & 511) << 2) + wid;
    int lane = threadIdx.x & 63;
    int hl = lane & 31;                               // pos within half
    int hi = lane >> 5;                               // which half
    int bt = __builtin_amdgcn_readfirstlane((b << 11) + t);

    const int* myinds = inds + bt * K_;
    // lane k holds inds[k] (k<20) for readlane-based scalar offsets
    int idxv = myinds[(lane < K_) ? lane : 0];

    const uint4* zrow = (const uint4*)(zth + (size_t)bt * F_);
    const uint4* crow = (const uint4*)(cth + (size_t)bt * F_);
    uint4 zv = zrow[hl];
    uint4 cv = crow[hl];

    const char* tbl = (const char*)zth;
    unsigned zbase = (unsigned)(b << 11) * 512u;      // batch base byte offset
    unsigned laneoff = (unsigned)hl * 16u;
    unsigned cbyte = (unsigned)CTOFF + (unsigned)bt * 512u;

    uint4 tv[NPAIR];
    {   // pair 0: lo = c row (positive), hi = inds[0]
        unsigned ohi = zbase + (unsigned)__builtin_amdgcn_readlane(idxv, 0) * 512u;
        tv[0] = *(const uint4*)(tbl + ((hi ? ohi : cbyte) + laneoff));
    }
#pragma unroll
    for (int p = 1; p < NPAIR; ++p) {
        // target k=2p -> inds[2p-1]; k=2p+1 -> inds[2p] (p=10 hi pads with inds[19])
        unsigned ilo = (unsigned)__builtin_amdgcn_readlane(idxv, 2 * p - 1);
        unsigned ihi = (unsigned)__builtin_amdgcn_readlane(idxv, (p == 10) ? 19 : 2 * p);
        unsigned off = zbase + (hi ? ihi : ilo) * 512u + laneoff;
        tv[p] = *(const uint4*)(tbl + off);
    }

    // hard scheduler fence: all 11 pair loads stay issued up-front
    __builtin_amdgcn_sched_barrier(0);

    float dz[NPAIR];
#pragma unroll
    for (int p = 0; p < NPAIR; ++p) {
        float d = fdot2f(tv[p].x, zv.x, 0.f);
        d = fdot2f(tv[p].y, zv.y, d);
        d = fdot2f(tv[p].z, zv.z, d);
        d = fdot2f(tv[p].w, zv.w, d);
        dz[p] = d;
    }

    // exact-equality mask (unit-f16 domain): cheap 1-uint screen,
    // uniform-branch full recheck (fires ~never on real data)
    unsigned mb = 0;
#pragma unroll
    for (int p = 0; p < NPAIR; ++p) {
        unsigned long long ball = __ballot(tv[p].x == cv.x);
        unsigned blo = (unsigned)ball, bhi = (unsigned)(ball >> 32);
        if (blo == 0xFFFFFFFFu || bhi == 0xFFFFFFFFu) {
            bool full = (tv[p].x == cv.x) && (tv[p].y == cv.y) &&
                        (tv[p].z == cv.z) && (tv[p].w == cv.w);
            unsigned long long b2 = __ballot(full);
            if ((unsigned)b2 == 0xFFFFFFFFu)          mb |= 1u << (2 * p);
            if ((unsigned)(b2 >> 32) == 0xFFFFFFFFu)  mb |= 1u << (2 * p + 1);
        }
    }
    mb &= ~1u;                                        // k=0 (positive) never masked

#pragma unroll
    for (int p = 0; p < NPAIR; ++p) dz[p] = dpp_half_sum(dz[p]);

    // collect: lanes 31/63 deposit pair results (same wave -> in-order DS, no barrier)
    int slotbase = wid * 32 + hi;
    if (hl == 31) {
#pragma unroll
        for (int p = 0; p < NPAIR; ++p) sd[slotbase + 2 * p] = dz[p];
    }

    // parallel epilogue: lane k finishes output k (logit = 2 * cosine)
    if (lane < OUTK) {
        float v = sd[wid * 32 + lane] * 2.0f;         // / TEMP, TEMP = 0.5
        if ((mb >> lane) & 1u) v = -INFINITY;
        out[(size_t)bt * OUTK + lane] = v;
    }
}

extern "C" void kernel_launch(void* const* d_in, const int* in_sizes, int n_in,
                              void* d_out, int out_size, void* d_ws, size_t ws_size,
                              hipStream_t stream)
{
    const float* z    = (const float*)d_in[0];
    const float* c    = (const float*)d_in[1];
    const int*   inds = (const int*)d_in[2];
    float* out = (float*)d_out;

    char* ws = (char*)d_ws;
    size_t th_bytes = (size_t)B_ * T_ * F_ * sizeof(ushort);  // 16 MB
    ushort* zth = (ushort*)ws;
    ushort* cth = (ushort*)(ws + th_bytes);                   // zth + CTOFF

    dim3 tb(256), tg(T_ / 32, B_, 2);
    transpose_norm2_kernel<<<tg, tb, 0, stream>>>(z, c, zth, cth);
    sim_kernel<<<dim3(B_ * T_ / 4), dim3(256), 0, stream>>>(zth, cth, inds, out);
}

// Round 12
// 44.684 us; speedup vs baseline: 1.9227x; 1.0024x over previous
//
#include <hip/hip_runtime.h>
#include <hip/hip_fp16.h>
#include <math.h>

#define B_ 16
#define F_ 256
#define T_ 2048
#define K_ 20
#define OUTK 21
#define NPAIR 11
#define CTOFF (B_ * T_ * F_ * 2)   // byte offset of cth table relative to zth (16 MB)

typedef _Float16 half2v __attribute__((ext_vector_type(2)));

__device__ __forceinline__ half2v h2(unsigned u) { return __builtin_bit_cast(half2v, u); }
__device__ __forceinline__ float fdot2f(unsigned a, unsigned b, float c) {
#if __has_builtin(__builtin_amdgcn_fdot2)
    return __builtin_amdgcn_fdot2(h2(a), h2(b), c, false);
#else
    half2v x = h2(a), y = h2(b);
    return fmaf((float)x[1], (float)y[1], fmaf((float)x[0], (float)y[0], c));
#endif
}

// Transpose z [F][T] / c [F][T+1] (drop col 0) -> UNIT-NORM f16 rows [T][F]
// per batch. Norm computed in exact fp32 from the staged column; rows are
// stored pre-divided by their norm so sim's dot IS the cosine (no norm
// gathers, no sqrt/div in sim). Zero-norm -> scale 0 -> dot 0 (matches
// reference's eps-clamped 0).
__global__ __launch_bounds__(256) void transpose_norm2_kernel(
    const float* __restrict__ z, const float* __restrict__ c,
    ushort* __restrict__ zth, ushort* __restrict__ cth)
{
    __shared__ float tile[256][33];  // 256 f x 32 t, +1 pad
    __shared__ float sc[32];         // per-column 1/norm
    int which = blockIdx.z;
    const float* src = which ? c : z;
    ushort* dst = which ? cth : zth;
    int Lsrc = which ? (T_ + 1) : T_;
    int co   = which;                 // c drops the start token

    int b  = blockIdx.y;
    int t0 = blockIdx.x * 32;
    const float* srcb = src + (size_t)b * F_ * Lsrc;
    int tl = threadIdx.x & 31;   // t within tile
    int fl = threadIdx.x >> 5;   // 0..7
#pragma unroll
    for (int i = 0; i < 32; ++i) {
        int f = i * 8 + fl;
        tile[f][tl] = srcb[(size_t)f * Lsrc + (t0 + tl + co)];
    }
    __syncthreads();
    if (threadIdx.x < 32) {
        float s = 0.f;
#pragma unroll 8
        for (int f = 0; f < 256; ++f) { float v = tile[f][threadIdx.x]; s += v * v; }
        float n = sqrtf(s);
        sc[threadIdx.x] = (n > 0.f) ? (1.0f / n) : 0.f;
    }
    __syncthreads();
    // write phase: pack 2 adjacent f into one uint; 128 lanes cover a row, 2 rows/iter
    int l   = threadIdx.x & 127;
    int rhi = threadIdx.x >> 7;
#pragma unroll
    for (int j2 = 0; j2 < 16; ++j2) {
        int row = j2 * 2 + rhi;
        float s  = sc[row];
        float a  = tile[2 * l][row] * s;
        float bb = tile[2 * l + 1][row] * s;
        unsigned u = ((unsigned)__half_as_ushort(__float2half(bb)) << 16)
                   |  (unsigned)__half_as_ushort(__float2half(a));
        unsigned* drow = (unsigned*)(dst + ((size_t)b * T_ + t0 + row) * F_);
        drow[l] = u;
    }
}

// Sum within each 32-lane half (pure VALU DPP). Valid in lane 31 (lo) / 63 (hi).
__device__ __forceinline__ float dpp_half_sum(float x) {
    x += __int_as_float(__builtin_amdgcn_mov_dpp(__float_as_int(x), 0x111, 0xF, 0xF, true)); // row_shr:1
    x += __int_as_float(__builtin_amdgcn_mov_dpp(__float_as_int(x), 0x112, 0xF, 0xF, true)); // row_shr:2
    x += __int_as_float(__builtin_amdgcn_mov_dpp(__float_as_int(x), 0x114, 0xF, 0xF, true)); // row_shr:4
    x += __int_as_float(__builtin_amdgcn_mov_dpp(__float_as_int(x), 0x118, 0xF, 0xF, true)); // row_shr:8
    x += __int_as_float(__builtin_amdgcn_mov_dpp(__float_as_int(x), 0x142, 0xF, 0xF, true)); // row_bcast:15
    return x;
}

// One 64-lane wave per (b,t). Two UNIT targets per wave-load (uint4: lanes
// 0-31 = target 2p, lanes 32-63 = target 2p+1). Offsets via inline readlane
// (pure SGPR, no array, no scratch). All 11 loads fenced in flight by
// sched_barrier(0). logit = 2 * dot (tables are unit rows). Parallel lane-k
// epilogue via tiny LDS.
// launch_bounds (256,6): ~85 VGPR cap -> 6 waves/SIMD (peak live ~70, fits).
__global__ __launch_bounds__(256, 6) void sim_kernel(
    const ushort* __restrict__ zth, const ushort* __restrict__ cth,
    const int* __restrict__ inds, float* __restrict__ out)
{
    __shared__ float sd[128];                         // 4 waves x 32 slots
    int i = blockIdx.x;                               // 8192 blocks, 4 waves each
    int b = (i & 7) | ((i >= 4096) ? 8 : 0);          // batch b on XCD b&7 (L2-resident table)
    int wid = threadIdx.x >> 6;
    int t = (((i >> 3) & 511) << 2) + wid;
    int lane = threadIdx.x & 63;
    int hl = lane & 31;                               // pos within half
    int hi = lane >> 5;                               // which half
    int bt = __builtin_amdgcn_readfirstlane((b << 11) + t);

    const int* myinds = inds + bt * K_;
    // lane k holds inds[k] (k<20) for readlane-based scalar offsets
    int idxv = myinds[(lane < K_) ? lane : 0];

    const uint4* zrow = (const uint4*)(zth + (size_t)bt * F_);
    const uint4* crow = (const uint4*)(cth + (size_t)bt * F_);
    uint4 zv = zrow[hl];
    uint4 cv = crow[hl];

    const char* tbl = (const char*)zth;
    unsigned zbase = (unsigned)(b << 11) * 512u;      // batch base byte offset
    unsigned laneoff = (unsigned)hl * 16u;
    unsigned cbyte = (unsigned)CTOFF + (unsigned)bt * 512u;

    uint4 tv[NPAIR];
    {   // pair 0: lo = c row (positive), hi = inds[0]
        unsigned ohi = zbase + (unsigned)__builtin_amdgcn_readlane(idxv, 0) * 512u;
        tv[0] = *(const uint4*)(tbl + ((hi ? ohi : cbyte) + laneoff));
    }
#pragma unroll
    for (int p = 1; p < NPAIR; ++p) {
        // target k=2p -> inds[2p-1]; k=2p+1 -> inds[2p] (p=10 hi pads with inds[19])
        unsigned ilo = (unsigned)__builtin_amdgcn_readlane(idxv, 2 * p - 1);
        unsigned ihi = (unsigned)__builtin_amdgcn_readlane(idxv, (p == 10) ? 19 : 2 * p);
        unsigned off = zbase + (hi ? ihi : ilo) * 512u + laneoff;
        tv[p] = *(const uint4*)(tbl + off);
    }

    // hard scheduler fence: all 11 pair loads stay issued up-front
    __builtin_amdgcn_sched_barrier(0);

    float dz[NPAIR];
#pragma unroll
    for (int p = 0; p < NPAIR; ++p) {
        float d = fdot2f(tv[p].x, zv.x, 0.f);
        d = fdot2f(tv[p].y, zv.y, d);
        d = fdot2f(tv[p].z, zv.z, d);
        d = fdot2f(tv[p].w, zv.w, d);
        dz[p] = d;
    }

    // exact-equality mask (unit-f16 domain): cheap 1-uint screen,
    // uniform-branch full recheck (fires ~never on real data)
    unsigned mb = 0;
#pragma unroll
    for (int p = 0; p < NPAIR; ++p) {
        unsigned long long ball = __ballot(tv[p].x == cv.x);
        unsigned blo = (unsigned)ball, bhi = (unsigned)(ball >> 32);
        if (blo == 0xFFFFFFFFu || bhi == 0xFFFFFFFFu) {
            bool full = (tv[p].x == cv.x) && (tv[p].y == cv.y) &&
                        (tv[p].z == cv.z) && (tv[p].w == cv.w);
            unsigned long long b2 = __ballot(full);
            if ((unsigned)b2 == 0xFFFFFFFFu)          mb |= 1u << (2 * p);
            if ((unsigned)(b2 >> 32) == 0xFFFFFFFFu)  mb |= 1u << (2 * p + 1);
        }
    }
    mb &= ~1u;                                        // k=0 (positive) never masked

#pragma unroll
    for (int p = 0; p < NPAIR; ++p) dz[p] = dpp_half_sum(dz[p]);

    // collect: lanes 31/63 deposit pair results (same wave -> in-order DS, no barrier)
    int slotbase = wid * 32 + hi;
    if (hl == 31) {
#pragma unroll
        for (int p = 0; p < NPAIR; ++p) sd[slotbase + 2 * p] = dz[p];
    }

    // parallel epilogue: lane k finishes output k (logit = 2 * cosine)
    if (lane < OUTK) {
        float v = sd[wid * 32 + lane] * 2.0f;         // / TEMP, TEMP = 0.5
        if ((mb >> lane) & 1u) v = -INFINITY;
        out[(size_t)bt * OUTK + lane] = v;
    }
}

extern "C" void kernel_launch(void* const* d_in, const int* in_sizes, int n_in,
                              void* d_out, int out_size, void* d_ws, size_t ws_size,
                              hipStream_t stream)
{
    const float* z    = (const float*)d_in[0];
    const float* c    = (const float*)d_in[1];
    const int*   inds = (const int*)d_in[2];
    float* out = (float*)d_out;

    char* ws = (char*)d_ws;
    size_t th_bytes = (size_t)B_ * T_ * F_ * sizeof(ushort);  // 16 MB
    ushort* zth = (ushort*)ws;
    ushort* cth = (ushort*)(ws + th_bytes);                   // zth + CTOFF

    dim3 tb(256), tg(T_ / 32, B_, 2);
    transpose_norm2_kernel<<<tg, tb, 0, stream>>>(z, c, zth, cth);
    sim_kernel<<<dim3(B_ * T_ / 4), dim3(256), 0, stream>>>(zth, cth, inds, out);
}